// Round 15
// baseline (112.611 us; speedup 1.0000x reference)
//
#include <hip/hip_runtime.h>
#include <hip/hip_bf16.h>

#define NROWS 32768
#define HH 128
#define ENTN 50000

typedef _Float16 f16x8 __attribute__((ext_vector_type(8)));
typedef __fp16 fp16x2 __attribute__((ext_vector_type(2)));
typedef float f32x4 __attribute__((ext_vector_type(4)));

// ws byte offsets
#define OFF_PEB 0                       // u32 [50000][128] packed {f16 K*m | f16 K*g} per colpair (25.6 MB)
#define OFF_WF  25600000                // f16 [16jb][4kt][64][8] acc-weight frags, j-interleaved, raw
#define OFF_PEF (OFF_WF + 65536)        // f16 [16jb][4kt][64][8] ent-weight frags, j-interleaved, raw
#define OFF_PO  (OFF_PEF + 65536)       // f32 [5][260] {m,g,m,g} per colpair, PRE-SCALED

#define KM 2.8853901f
#define KG (-1.4426950f)
#define RSTR 272                        // acc LDS row stride (256 + 16 pad; 16B-aligned, optimal for b128)
#define HALF (32 * RSTR)

#if defined(__has_builtin)
#if __has_builtin(__builtin_amdgcn_exp2f)
#define FEXP2(x) __builtin_amdgcn_exp2f(x)
#endif
#endif
#ifndef FEXP2
__device__ __forceinline__ float __fexp2_asm(float x) {
    float r; asm("v_exp_f32 %0, %1" : "=v"(r) : "v"(x)); return r;
}
#define FEXP2(x) __fexp2_asm(x)
#endif

__device__ __forceinline__ unsigned pk2(float a, float b) {
    fp16x2 h = __builtin_amdgcn_cvt_pkrtz(a, b);
    unsigned u; __builtin_memcpy(&u, &h, 4); return u;
}
__device__ __forceinline__ float h2f(unsigned short s) {
    _Float16 h; __builtin_memcpy(&h, &s, 2); return (float)h;
}

// ---------------- prep: WF, PEF, PO(pre-scaled), out tail ----------------
__global__ void prep_kernel(const float* __restrict__ op_table,
                            const float* __restrict__ non_table,
                            const float* __restrict__ Wm, const float* __restrict__ bm,
                            const float* __restrict__ Wg, const float* __restrict__ bg,
                            char* __restrict__ ws, float* __restrict__ out) {
    int idx = blockIdx.x * blockDim.x + threadIdx.x;
    if (idx < 32768) {                           // WF: acc-path frags (raw)
        int e = idx;
        int jj = e & 7, l = (e >> 3) & 63, kt = (e >> 9) & 3, jb = e >> 11;
        int j = jb * 16 + (l & 15);
        int c = j >> 1, p = j & 1;
        int k = kt * 32 + (l >> 4) * 8 + jj;
        const float* Wrow = p ? (Wg + (size_t)c * 384) : (Wm + (size_t)c * 384);
        ((_Float16*)(ws + OFF_WF))[e] = (_Float16)Wrow[256 + k];
    } else if (idx < 65536) {                    // PEF: ent-path frags (raw)
        int e = idx - 32768;
        int jj = e & 7, l = (e >> 3) & 63, kt = (e >> 9) & 3, jb = e >> 11;
        int j = jb * 16 + (l & 15);
        int c = j >> 1, p = j & 1;
        int k = kt * 32 + (l >> 4) * 8 + jj;
        const float* Wrow = p ? (Wg + (size_t)c * 384) : (Wm + (size_t)c * 384);
        ((_Float16*)(ws + OFF_PEF))[e] = (_Float16)Wrow[128 + k];
    } else if (idx < 66816) {                    // PO: pre-scaled, colpair-interleaved
        int e = idx - 65536;
        int o = e >> 8, jj = e & 255;
        int c = jj >> 1, p = jj & 1;
        const float* Wrow = p ? (Wg + (size_t)c * 384) : (Wm + (size_t)c * 384);
        float s = p ? bg[c] : bm[c];
        for (int i = 0; i < 128; ++i) s += op_table[o * HH + i] * Wrow[i];
        s *= (p ? KG : KM);
        ((float*)(ws + OFF_PO))[o * 260 + (c >> 1) * 4 + 2 * (c & 1) + p] = s;
    } else if (idx < 66944) {
        int j = idx - 66816;
        out[(size_t)NROWS * HH + j] = non_table[j];
    }
}

// ---------------- PEB = pack(K * (W_ent @ ent^T)): f32 source, A reused across 4 jb ----------------
__global__ __launch_bounds__(256, 4)
void pe_kernel(const float* __restrict__ ent_table, char* __restrict__ ws) {
    const f16x8* PEF = (const f16x8*)(ws + OFF_PEF);
    unsigned* PEB = (unsigned*)(ws + OFF_PEB);
    int tid = threadIdx.x, w = tid >> 6, l = tid & 63, lr = l & 15, lg = (l >> 4) & 3;
    int e0 = blockIdx.x * 32;

    f16x8 WB[4][4];
    #pragma unroll
    for (int u = 0; u < 4; ++u)
        #pragma unroll
        for (int kt = 0; kt < 4; ++kt)
            WB[u][kt] = PEF[((4 * w + u) * 4 + kt) * 64 + l];

    f32x4 C[2][4];
    #pragma unroll
    for (int rt = 0; rt < 2; ++rt)
        #pragma unroll
        for (int u = 0; u < 4; ++u) C[rt][u] = (f32x4){0.f, 0.f, 0.f, 0.f};

    #pragma unroll
    for (int kt = 0; kt < 4; ++kt) {
        #pragma unroll
        for (int rt = 0; rt < 2; ++rt) {
            int e = e0 + rt * 16 + lr;
            if (e >= ENTN) e = ENTN - 1;
            const float4* s = (const float4*)(ent_table + (size_t)e * HH + kt * 32 + lg * 8);
            float4 v0 = s[0], v1 = s[1];
            unsigned u4[4] = {pk2(v0.x, v0.y), pk2(v0.z, v0.w),
                              pk2(v1.x, v1.y), pk2(v1.z, v1.w)};
            f16x8 A; __builtin_memcpy(&A, u4, 16);
            #pragma unroll
            for (int u = 0; u < 4; ++u)
                C[rt][u] = __builtin_amdgcn_mfma_f32_16x16x32_f16(WB[u][kt], A, C[rt][u], 0, 0, 0);
        }
    }
    #pragma unroll
    for (int rt = 0; rt < 2; ++rt) {
        int e = e0 + rt * 16 + lr;
        if (e < ENTN) {
            #pragma unroll
            for (int u = 0; u < 4; ++u) {
                uint2 st;
                st.x = pk2(C[rt][u][0] * KM, C[rt][u][1] * KG);
                st.y = pk2(C[rt][u][2] * KM, C[rt][u][3] * KG);
                *(uint2*)(PEB + (size_t)e * HH + (4 * w + u) * 8 + 2 * lg) = st;
            }
        }
    }
}

// ---------------- fused 17-step chain (v14 + eo64 packing) ----------------
__global__ __launch_bounds__(1024, 8)
void chain_kernel(const float* __restrict__ ent_table,
                  const int* __restrict__ ops_idx,
                  const int* __restrict__ ents_idx,
                  const int* __restrict__ left_idx,
                  const char* __restrict__ ws, float* __restrict__ out) {
    __shared__ char Abuf[2 * HALF];              // [2p][32r][272B]
    __shared__ unsigned long long eo64[17 * 16]; // [t][lr]: {row 16+lr}<<32 | {row lr}, (e<<9)|o
    __shared__ float po_s[5 * 260];

    const char* PEBc = ws + OFF_PEB;
    const f16x8* WF2p = (const f16x8*)(ws + OFF_WF);
    const float* POg = (const float*)(ws + OFF_PO);

    int tid = threadIdx.x;
    int jb = tid >> 6, l = tid & 63, lr = l & 15, lg = (l >> 4) & 3;
    int row0 = blockIdx.x * 32;
    int c1 = jb * 8 + 2 * lg;

    if (tid < 272) {
        int r = tid & 15, t = tid >> 4;
        unsigned lo, hi;
        if (t < 16) {
            lo = ((unsigned)ents_idx[(row0 + r) * 17 + 15 - t] << 9)
               | (unsigned)ops_idx[(row0 + r) * 16 + 15 - t];
            hi = ((unsigned)ents_idx[(row0 + 16 + r) * 17 + 15 - t] << 9)
               | (unsigned)ops_idx[(row0 + 16 + r) * 16 + 15 - t];
        } else {
            lo = ((unsigned)left_idx[row0 + r] << 9) | 4u;
            hi = ((unsigned)left_idx[row0 + 16 + r] << 9) | 4u;
        }
        eo64[t * 16 + r] = ((unsigned long long)hi << 32) | lo;
    }
    for (int i = tid; i < 1300; i += 1024) po_s[i] = POg[i];

    f16x8 WH[4];
    #pragma unroll
    for (int kt = 0; kt < 4; ++kt)
        WH[kt] = WF2p[(jb * 4 + kt) * 64 + l];

    {   // acc0 init -> parity 0
        int r = tid >> 5, sub = tid & 31;
        int e = ents_idx[(row0 + r) * 17 + 16];
        float4 v = *(const float4*)(ent_table + (size_t)e * HH + sub * 4);
        uint2 d;
        d.x = pk2(v.x, v.y);
        d.y = pk2(v.z, v.w);
        *(uint2*)(Abuf + r * RSTR + sub * 8) = d;
    }
    __syncthreads();

    int rb = lr * RSTR + lg * 16;            // MFMA B-operand read base
    int wb = lr * RSTR + jb * 16 + 4 * lg;   // acc write base
    const char* pebBase = PEBc + c1 * 4;
    const float* poBase = po_s + (4 * jb + lg) * 4;
    const unsigned long long* eoB = eo64 + lr;

    const f32x4 K4 = (f32x4){KM, KG, KM, KG};

    // prologue: gather for t=0
    unsigned long long v64 = eoB[0];
    unsigned va = (unsigned)v64, vb = (unsigned)(v64 >> 32);
    uint2 pea = *(const uint2*)(pebBase + (va & 0xFFFFFE00u));
    uint2 peb = *(const uint2*)(pebBase + (vb & 0xFFFFFE00u));

#define DO_STEP(T, RD, WR, FINAL)                                               \
    {                                                                           \
        uint2 npea, npeb; unsigned nva = 0, nvb = 0;                            \
        if (!(FINAL)) {                                                         \
            unsigned long long n64 = eoB[((T) + 1) * 16];                       \
            nva = (unsigned)n64; nvb = (unsigned)(n64 >> 32);                   \
            npea = *(const uint2*)(pebBase + (nva & 0xFFFFFE00u));              \
            npeb = *(const uint2*)(pebBase + (nvb & 0xFFFFFE00u));              \
        }                                                                       \
        f32x4 poa = *(const f32x4*)(poBase + (va & 7u) * 260);                  \
        f32x4 pob = *(const f32x4*)(poBase + (vb & 7u) * 260);                  \
        f32x4 C0 = (f32x4){0.f, 0.f, 0.f, 0.f};                                 \
        f32x4 C1 = (f32x4){0.f, 0.f, 0.f, 0.f};                                 \
        _Pragma("unroll")                                                       \
        for (int kt = 0; kt < 4; ++kt) {                                        \
            f16x8 A0 = *(const f16x8*)(Abuf + rb + (RD) + kt * 64);             \
            f16x8 A1 = *(const f16x8*)(Abuf + rb + (RD) + 16 * RSTR + kt * 64); \
            C0 = __builtin_amdgcn_mfma_f32_16x16x32_f16(WH[kt], A0, C0, 0, 0, 0); \
            C1 = __builtin_amdgcn_mfma_f32_16x16x32_f16(WH[kt], A1, C1, 0, 0, 0); \
        }                                                                       \
        _Pragma("unroll")                                                       \
        for (int rt = 0; rt < 2; ++rt) {                                        \
            uint2 pe = rt ? peb : pea;                                          \
            f32x4 po = rt ? pob : poa;                                          \
            f32x4 z = rt ? C1 : C0;                                             \
            f32x4 pef;                                                          \
            pef[0] = h2f((unsigned short)pe.x);                                 \
            pef[1] = h2f((unsigned short)(pe.x >> 16));                         \
            pef[2] = h2f((unsigned short)pe.y);                                 \
            pef[3] = h2f((unsigned short)(pe.y >> 16));                         \
            f32x4 s4 = pef + po;                                                \
            f32x4 a = z * K4 + s4;                                              \
            f32x4 ev;                                                           \
            ev[0] = FEXP2(a[0]); ev[1] = FEXP2(a[1]);                           \
            ev[2] = FEXP2(a[2]); ev[3] = FEXP2(a[3]);                           \
            f32x4 p1 = ev + 1.0f;                                               \
            float r1 = (ev[0] - 1.f) * __builtin_amdgcn_rcpf(p1[0] * p1[1]);    \
            float r2 = (ev[2] - 1.f) * __builtin_amdgcn_rcpf(p1[2] * p1[3]);    \
            if (FINAL) {                                                        \
                float2 o2 = make_float2(r1, r2);                                \
                *(float2*)(out + (size_t)(row0 + rt * 16 + lr) * HH + c1) = o2; \
            } else {                                                            \
                *(unsigned*)(Abuf + wb + (WR) + rt * 16 * RSTR) = pk2(r1, r2);  \
            }                                                                   \
        }                                                                       \
        __syncthreads();                                                        \
        if (!(FINAL)) { pea = npea; peb = npeb; va = nva; vb = nvb; }           \
    }

    for (int tb = 0; tb < 8; ++tb) {
        int t0 = 2 * tb;
        DO_STEP(t0, 0, HALF, 0)
        DO_STEP(t0 + 1, HALF, 0, 0)
    }
    DO_STEP(16, 0, HALF, 1)
#undef DO_STEP
}

extern "C" void kernel_launch(void* const* d_in, const int* in_sizes, int n_in,
                              void* d_out, int out_size, void* d_ws, size_t ws_size,
                              hipStream_t stream) {
    const float* ent_table = (const float*)d_in[0];
    const float* op_table  = (const float*)d_in[1];
    const float* non_table = (const float*)d_in[2];
    const float* Wm        = (const float*)d_in[3];
    const float* bm        = (const float*)d_in[4];
    const float* Wg        = (const float*)d_in[5];
    const float* bg        = (const float*)d_in[6];
    const int* ops_idx     = (const int*)d_in[7];
    const int* ents_idx    = (const int*)d_in[8];
    const int* left_idx    = (const int*)d_in[9];
    float* out = (float*)d_out;
    char* ws = (char*)d_ws;

    prep_kernel<<<262, 256, 0, stream>>>(op_table, non_table, Wm, bm, Wg, bg, ws, out);
    pe_kernel<<<1563, 256, 0, stream>>>(ent_table, ws);
    chain_kernel<<<NROWS / 32, 1024, 0, stream>>>(ent_table, ops_idx, ents_idx,
                                                  left_idx, ws, out);
}